// Round 1
// baseline (1150.865 us; speedup 1.0000x reference)
//
#include <hip/hip_runtime.h>

// SheafConvLayer:
//   out[n] = relu( W_self[n] @ x[n] + b_self[n]
//                  + sum_{e: dst[e]==n} ( W_edge[e] @ x[src[e]] + b_edge[e] ) )
// D_IN = D_OUT = 16. One wave (64 lanes) per 16x16 matrix:
//   lane l reads float4 at flat offset 4l of the matrix -> o = l>>2, i0 = (l&3)*4.
//   dot4 + shfl_xor(1) + shfl_xor(2) reduces the 4-lane group; every lane in the
//   group then holds the full row-dot, lane o in [0,16) pulls it from lane 4o.

#define DD 16

__global__ void sheaf_self_kernel(const float* __restrict__ x,
                                  const float* __restrict__ w_self,
                                  const float* __restrict__ b_self,
                                  float* __restrict__ out,
                                  int n_nodes) {
    const int lane  = threadIdx.x & 63;
    const int wave  = (int)((blockIdx.x * blockDim.x + threadIdx.x) >> 6);
    const int nwav  = (int)((gridDim.x * blockDim.x) >> 6);
    const int qi    = lane & 3;            // quarter of the input row

    for (int n = wave; n < n_nodes; n += nwav) {
        const float4 w  = *(const float4*)(w_self + (size_t)n * (DD * DD) + lane * 4);
        const float4 xv = *(const float4*)(x      + (size_t)n * DD + qi * 4);
        float p = w.x * xv.x + w.y * xv.y + w.z * xv.z + w.w * xv.w;
        p += __shfl_xor(p, 1);
        p += __shfl_xor(p, 2);                 // all 4 lanes of the group hold the sum
        float v = __shfl(p, (lane & 15) * 4);  // lane o <- lane 4o
        if (lane < DD) {
            out[(size_t)n * DD + lane] = v + b_self[(size_t)n * DD + lane];
        }
    }
}

__global__ void sheaf_edge_kernel(const float* __restrict__ x,
                                  const int* __restrict__ edge_index, // [2][n_edges]
                                  const float* __restrict__ w_edge,
                                  const float* __restrict__ b_edge,
                                  float* __restrict__ out,
                                  int n_edges) {
    const int lane  = threadIdx.x & 63;
    const int wave  = (int)((blockIdx.x * blockDim.x + threadIdx.x) >> 6);
    const int nwav  = (int)((gridDim.x * blockDim.x) >> 6);
    const int qi    = lane & 3;

    for (int e = wave; e < n_edges; e += nwav) {
        const int src = edge_index[e];
        const int dst = edge_index[n_edges + e];
        const float4 w  = *(const float4*)(w_edge + (size_t)e * (DD * DD) + lane * 4);
        const float4 xv = *(const float4*)(x + (size_t)src * DD + qi * 4);
        float p = w.x * xv.x + w.y * xv.y + w.z * xv.z + w.w * xv.w;
        p += __shfl_xor(p, 1);
        p += __shfl_xor(p, 2);
        float v = __shfl(p, (lane & 15) * 4);
        if (lane < DD) {
            atomicAdd(&out[(size_t)dst * DD + lane],
                      v + b_edge[(size_t)e * DD + lane]);
        }
    }
}

__global__ void sheaf_relu_kernel(float* __restrict__ out, int total4) {
    int i = (int)(blockIdx.x * blockDim.x + threadIdx.x);
    const int stride = (int)(gridDim.x * blockDim.x);
    for (; i < total4; i += stride) {
        float4 v = ((float4*)out)[i];
        v.x = fmaxf(v.x, 0.f);
        v.y = fmaxf(v.y, 0.f);
        v.z = fmaxf(v.z, 0.f);
        v.w = fmaxf(v.w, 0.f);
        ((float4*)out)[i] = v;
    }
}

extern "C" void kernel_launch(void* const* d_in, const int* in_sizes, int n_in,
                              void* d_out, int out_size, void* d_ws, size_t ws_size,
                              hipStream_t stream) {
    const float* x       = (const float*)d_in[0];
    const int*   ei      = (const int*)  d_in[1];
    const float* w_edge  = (const float*)d_in[2];
    const float* w_self  = (const float*)d_in[3];
    const float* b_edge  = (const float*)d_in[4];
    const float* b_self  = (const float*)d_in[5];
    float*       out     = (float*)d_out;

    const int n_nodes = in_sizes[0] / DD;       // 100000
    const int n_edges = in_sizes[1] / 2;        // 800000

    // 1) self term writes out (overwrites 0xAA poison)
    sheaf_self_kernel<<<1024, 256, 0, stream>>>(x, w_self, b_self, out, n_nodes);
    // 2) edge messages scatter-add into out
    sheaf_edge_kernel<<<2048, 256, 0, stream>>>(x, ei, w_edge, b_edge, out, n_edges);
    // 3) relu in place
    sheaf_relu_kernel<<<512, 256, 0, stream>>>(out, n_nodes * DD / 4);
}

// Round 2
// 1123.959 us; speedup vs baseline: 1.0239x; 1.0239x over previous
//
#include <hip/hip_runtime.h>

// SheafConvLayer:
//   out[n] = relu( W_self[n] @ x[n] + b_self[n]
//                  + sum_{e: dst[e]==n} ( W_edge[e] @ x[src[e]] + b_edge[e] ) )
// D_IN = D_OUT = 16, fp32.
//
// R2 layout: 16 lanes per 16x16 matrix, one-shot grid (no grid-stride loop).
//   thread t -> matrix m = t>>4, output row o = t&15.
//   Lane reads its 64 B weight row as 4x float4 (independent loads, deep ILP),
//   the 64 B input vector as 4x float4 (broadcast within the 16-lane group via L1),
//   dot16 in-register, then ONE atomicAdd per lane (all 64 lanes active).
// Rationale: R1 was ~3x over BW roofline -> latency-bound loop (8 waves/SIMD,
// dependent load->shfl->masked-atomic chain per iteration). One-shot grid with
// 50k blocks queued gives the scheduler unbounded TLP; loads per thread are all
// independent.

#define DD 16

__global__ void sheaf_self_kernel(const float* __restrict__ x,
                                  const float* __restrict__ w_self,
                                  const float* __restrict__ b_self,
                                  float* __restrict__ out,
                                  int n_nodes) {
    const int t = (int)(blockIdx.x * blockDim.x + threadIdx.x);
    const int n = t >> 4;
    const int o = t & 15;
    if (n >= n_nodes) return;

    const float4* wr = (const float4*)(w_self + (size_t)n * (DD * DD) + o * DD);
    const float4* xr = (const float4*)(x + (size_t)n * DD);
    float4 w0 = wr[0], w1 = wr[1], w2 = wr[2], w3 = wr[3];
    float4 x0 = xr[0], x1 = xr[1], x2 = xr[2], x3 = xr[3];

    float acc = b_self[(size_t)n * DD + o];
    acc += w0.x * x0.x + w0.y * x0.y + w0.z * x0.z + w0.w * x0.w;
    acc += w1.x * x1.x + w1.y * x1.y + w1.z * x1.z + w1.w * x1.w;
    acc += w2.x * x2.x + w2.y * x2.y + w2.z * x2.z + w2.w * x2.w;
    acc += w3.x * x3.x + w3.y * x3.y + w3.z * x3.z + w3.w * x3.w;

    out[(size_t)n * DD + o] = acc;
}

__global__ void sheaf_edge_kernel(const float* __restrict__ x,
                                  const int* __restrict__ edge_index, // [2][n_edges]
                                  const float* __restrict__ w_edge,
                                  const float* __restrict__ b_edge,
                                  float* __restrict__ out,
                                  int n_edges) {
    const int t = (int)(blockIdx.x * blockDim.x + threadIdx.x);
    const int e = t >> 4;
    const int o = t & 15;
    if (e >= n_edges) return;

    const int src = edge_index[e];             // broadcast within 16-lane group
    const int dst = edge_index[n_edges + e];

    const float4* wr = (const float4*)(w_edge + (size_t)e * (DD * DD) + o * DD);
    const float4* xr = (const float4*)(x + (size_t)src * DD);
    float4 w0 = wr[0], w1 = wr[1], w2 = wr[2], w3 = wr[3];
    float4 x0 = xr[0], x1 = xr[1], x2 = xr[2], x3 = xr[3];

    float acc = b_edge[(size_t)e * DD + o];
    acc += w0.x * x0.x + w0.y * x0.y + w0.z * x0.z + w0.w * x0.w;
    acc += w1.x * x1.x + w1.y * x1.y + w1.z * x1.z + w1.w * x1.w;
    acc += w2.x * x2.x + w2.y * x2.y + w2.z * x2.z + w2.w * x2.w;
    acc += w3.x * x3.x + w3.y * x3.y + w3.z * x3.z + w3.w * x3.w;

    atomicAdd(&out[(size_t)dst * DD + o], acc);
}

__global__ void sheaf_relu_kernel(float* __restrict__ out, int total4) {
    const int i = (int)(blockIdx.x * blockDim.x + threadIdx.x);
    if (i >= total4) return;
    float4 v = ((float4*)out)[i];
    v.x = fmaxf(v.x, 0.f);
    v.y = fmaxf(v.y, 0.f);
    v.z = fmaxf(v.z, 0.f);
    v.w = fmaxf(v.w, 0.f);
    ((float4*)out)[i] = v;
}

extern "C" void kernel_launch(void* const* d_in, const int* in_sizes, int n_in,
                              void* d_out, int out_size, void* d_ws, size_t ws_size,
                              hipStream_t stream) {
    const float* x      = (const float*)d_in[0];
    const int*   ei     = (const int*)  d_in[1];
    const float* w_edge = (const float*)d_in[2];
    const float* w_self = (const float*)d_in[3];
    const float* b_edge = (const float*)d_in[4];
    const float* b_self = (const float*)d_in[5];
    float*       out    = (float*)d_out;

    const int n_nodes = in_sizes[0] / DD;   // 100000
    const int n_edges = in_sizes[1] / 2;    // 800000

    // 1) self term: writes every out element (clears 0xAA poison)
    {
        const int threads = n_nodes * DD;                 // one thread per (n, o)
        sheaf_self_kernel<<<(threads + 255) / 256, 256, 0, stream>>>(
            x, w_self, b_self, out, n_nodes);
    }
    // 2) edge messages: scatter-add, one thread per (e, o)
    {
        const int threads = n_edges * DD;
        sheaf_edge_kernel<<<(threads + 255) / 256, 256, 0, stream>>>(
            x, ei, w_edge, b_edge, out, n_edges);
    }
    // 3) relu in place
    {
        const int total4 = n_nodes * DD / 4;
        sheaf_relu_kernel<<<(total4 + 255) / 256, 256, 0, stream>>>(out, total4);
    }
}